// Round 4
// baseline (207.645 us; speedup 1.0000x reference)
//
#include <hip/hip_runtime.h>
#include <stdint.h>

#define DIM_W 160
#define DIM_H 192
#define DIM_D 160
#define DIM_B 2

constexpr int TW = 16;      // output tile width (W)
constexpr int TH = 32;      // output tile height (H), P=4 px/thread
constexpr int P  = 4;
constexpr int CH = 28;      // depth outputs per chunk; 36 slices = 4 x unroll-9
constexpr int NCH = 6;      // ceil(160/28)
constexpr int RH = TH + 8;  // 40 region rows incl halo
constexpr float INV_K = 1.0f / 729.0f;
constexpr double NTOT = 9830400.0; // 2*160*192*160

typedef unsigned int u32;
typedef __attribute__((address_space(1))) const u32 gu32;
typedef __attribute__((address_space(3))) u32 lu32;

__global__ void init_kernel(float* out, float* ws) {
    out[0] = 0.0f;
    ws[0] = 0.0f; ws[1] = 0.0f; ws[2] = 0.0f; ws[3] = 0.0f;
}

__device__ __forceinline__ void gload16(const float* g, float* l) {
    __builtin_amdgcn_global_load_lds((gu32*)g, (lu32*)l, 16, 0, 0);
}

__global__ __launch_bounds__(128, 2)
void lncc3d_kernel(const float* __restrict__ I,
                   const float* __restrict__ T,
                   const float* __restrict__ zsrc,
                   float* __restrict__ out)
{
    // region: [field][row][word], 32 words/row = 128B (wave-contiguous for glds),
    // per-row f4 rotation: physical_f4 = (logical_f4 + row) & 7 (applied at global src)
    __shared__ __align__(16) float sR[2][RH][32];
    // W-sums (I,T,II,TT): rotated columns (c + r) & 15, stride 16 f4 (no pad needed)
    __shared__ __align__(16) float4 wA[RH][16];
    // W-sums IT, TRANSPOSED [w][row], stride 44 (16B-aligned rows, ~2-way max)
    __shared__ __align__(16) float  wB[16][44];
    __shared__ float red[2];

    const int tid  = threadIdx.x;
    const int wo   = tid & 15;            // output w within tile
    const int hb   = (tid >> 4) << 2;     // base local h: 0,4,...,28
    const int lane = tid & 63;
    const int wid  = tid >> 6;            // wave 0: field I, wave 1: field T

    const int bw = blockIdx.x, bh = blockIdx.y, bz = blockIdx.z;
    const int b  = bz / NCH;
    const int ch = bz - b * NCH;
    const int w0 = bw * TW, h0 = bh * TH, d0 = ch * CH;
    const int dEnd = min(d0 + CH, DIM_D);

    const int plane = DIM_H * DIM_W;
    const float* Fb = (wid == 0 ? I : T) + (size_t)b * DIM_D * plane;

    // glds addressing: chunk cc covers rows 8cc..8cc+7; lane -> (row, physical f4)
    const int crow = lane >> 3;
    const int pc4  = lane & 7;
    int boff[5];
#pragma unroll
    for (int cc = 0; cc < 5; ++cc) {
        const int row = cc * 8 + crow;
        const int lc4 = (pc4 - row) & 7;            // logical f4 for this physical slot
        const int gh  = h0 - 4 + row;
        const int gw  = w0 - 8 + (lc4 << 2);
        const bool ib = (gh >= 0 && gh < DIM_H && gw >= 0 && gw < DIM_W);
        boff[cc] = ib ? (gh * DIM_W + gw) : -1;
    }

    // stage1 ids: pass A = all threads (rows 0..31), pass B = tid<32 (rows 32..39)
    const int r1 = tid >> 2;
    const int g1 = tid & 3;

    float rgI[P][9], rgT[P][9], rgII[P][9], rgTT[P][9], rgIT[P][9];
    float rnI[P], rnT[P], rnII[P], rnTT[P], rnIT[P];
#pragma unroll
    for (int p = 0; p < P; ++p) {
        rnI[p] = rnT[p] = rnII[p] = rnTT[p] = rnIT[p] = 0.0f;
#pragma unroll
        for (int q = 0; q < 9; ++q) {
            rgI[p][q] = rgT[p][q] = rgII[p][q] = rgTT[p][q] = rgIT[p][q] = 0.0f;
        }
    }
    float acc = 0.0f;

    const int sStart = d0 - 4;

    // prologue: stage slice sStart (if valid) directly into LDS
    if (sStart >= 0) {
        const float* Fs = Fb + (size_t)sStart * plane;
#pragma unroll
        for (int cc = 0; cc < 5; ++cc) {
            const float* gp = (boff[cc] >= 0) ? (Fs + boff[cc]) : zsrc;
            gload16(gp, &sR[wid][cc * 8][0]);
        }
    }
    __syncthreads();

    for (int t = 0; t < 4; ++t) {
#pragma unroll
        for (int j = 0; j < 9; ++j) {
            const int idx = t * 9 + j;
            const int s   = sStart + idx;
            const bool vs = (s >= 0) && (s < DIM_D);

            // ---- stage 1: 9-wide W sums (sliding window, 4-output groups) ----
            if (vs) {
                auto st1 = [&](const int r, const int g) {
                    const float* rI_ = &sR[0][r][0];
                    const float* rT_ = &sR[1][r][0];
                    const int q0 = ((g + 1 + r) & 7) << 2;
                    const int q1 = ((g + 2 + r) & 7) << 2;
                    const int q2 = ((g + 3 + r) & 7) << 2;
                    const float4 ia  = *(const float4*)(rI_ + q0);
                    const float4 ib4 = *(const float4*)(rI_ + q1);
                    const float4 ic4 = *(const float4*)(rI_ + q2);
                    const float4 ta  = *(const float4*)(rT_ + q0);
                    const float4 tb4 = *(const float4*)(rT_ + q1);
                    const float4 tc4 = *(const float4*)(rT_ + q2);
                    const float iv[12] = {ia.x, ia.y, ia.z, ia.w, ib4.x, ib4.y, ib4.z, ib4.w,
                                          ic4.x, ic4.y, ic4.z, ic4.w};
                    const float tv[12] = {ta.x, ta.y, ta.z, ta.w, tb4.x, tb4.y, tb4.z, tb4.w,
                                          tc4.x, tc4.y, tc4.z, tc4.w};
                    float aI = 0.f, aT = 0.f, aII = 0.f, aTT = 0.f, aIT = 0.f;
#pragma unroll
                    for (int k = 0; k < 9; ++k) {
                        aI += iv[k]; aT += tv[k];
                        aII = fmaf(iv[k], iv[k], aII);
                        aTT = fmaf(tv[k], tv[k], aTT);
                        aIT = fmaf(iv[k], tv[k], aIT);
                    }
                    const int c0 = g << 2;
                    wA[r][(c0 + r) & 15] = make_float4(aI, aT, aII, aTT);
                    wB[c0][r] = aIT;
#pragma unroll
                    for (int q = 1; q < 4; ++q) {
                        const float ni = iv[8 + q], oi = iv[q - 1];
                        const float nt = tv[8 + q], ot = tv[q - 1];
                        aI += ni - oi; aT += nt - ot;
                        aII = fmaf(ni, ni, fmaf(oi, -oi, aII));
                        aTT = fmaf(nt, nt, fmaf(ot, -ot, aTT));
                        aIT = fmaf(ni, nt, fmaf(oi, -ot, aIT));
                        wA[r][(c0 + q + r) & 15] = make_float4(aI, aT, aII, aTT);
                        wB[c0 + q][r] = aIT;
                    }
                };
                st1(r1, g1);
                if (tid < 32) st1(32 + r1, g1);
            }
            __syncthreads();

            // ---- prefetch next slice into region (overlaps stage 2) ----
            {
                const int sn = s + 1;
                if (idx < 35 && sn >= 0 && sn < DIM_D) {
                    const float* Fs = Fb + (size_t)sn * plane;
#pragma unroll
                    for (int cc = 0; cc < 5; ++cc) {
                        const float* gp = (boff[cc] >= 0) ? (Fs + boff[cc]) : zsrc;
                        gload16(gp, &sR[wid][cc * 8][0]);
                    }
                }
            }

            // ---- stage 2: 9-tall H sums, 4 px via sliding window; rings; emit ----
            float sx = 0.f, sy = 0.f, sz = 0.f, sw = 0.f, sb = 0.f;
            float4 A0, A1, A2, B0, B1, B2;
            if (vs) {
                B0 = *(const float4*)&wB[wo][hb];
                B1 = *(const float4*)&wB[wo][hb + 4];
                B2 = *(const float4*)&wB[wo][hb + 8];
                A0 = wA[hb + 0][(wo + hb + 0) & 15];
                A1 = wA[hb + 1][(wo + hb + 1) & 15];
                A2 = wA[hb + 2][(wo + hb + 2) & 15];
                sx = A0.x + A1.x + A2.x; sy = A0.y + A1.y + A2.y;
                sz = A0.z + A1.z + A2.z; sw = A0.w + A1.w + A2.w;
#pragma unroll
                for (int k = 3; k < 9; ++k) {
                    const float4 Ak = wA[hb + k][(wo + hb + k) & 15];
                    sx += Ak.x; sy += Ak.y; sz += Ak.z; sw += Ak.w;
                }
                sb = B0.x + B0.y + B0.z + B0.w + B1.x + B1.y + B1.z + B1.w + B2.x;
            } else {
                A0 = A1 = A2 = make_float4(0.f, 0.f, 0.f, 0.f);
                B0 = B1 = B2 = make_float4(0.f, 0.f, 0.f, 0.f);
            }

            const bool em = (s >= d0 + 4) && ((s - 4) < dEnd);

#define UPD(p) \
            rnI[p]  += sx - rgI[p][j];  rgI[p][j]  = sx; \
            rnT[p]  += sy - rgT[p][j];  rgT[p][j]  = sy; \
            rnII[p] += sz - rgII[p][j]; rgII[p][j] = sz; \
            rnTT[p] += sw - rgTT[p][j]; rgTT[p][j] = sw; \
            rnIT[p] += sb - rgIT[p][j]; rgIT[p][j] = sb;
#define EMIT(p) if (em) { \
            const float cr  = rnIT[p] - rnI[p] * rnT[p] * INV_K; \
            const float iv_ = rnII[p] - rnI[p] * rnI[p] * INV_K; \
            const float tv_ = rnTT[p] - rnT[p] * rnT[p] * INV_K; \
            acc += cr * cr / (tv_ * iv_ + 1e-5f); }

            UPD(0); EMIT(0);
            if (vs) {
                const float4 A9 = wA[hb + 9][(wo + hb + 9) & 15];
                sx += A9.x - A0.x; sy += A9.y - A0.y;
                sz += A9.z - A0.z; sw += A9.w - A0.w;
                sb += B2.y - B0.x;
            }
            UPD(1); EMIT(1);
            if (vs) {
                const float4 Aa = wA[hb + 10][(wo + hb + 10) & 15];
                sx += Aa.x - A1.x; sy += Aa.y - A1.y;
                sz += Aa.z - A1.z; sw += Aa.w - A1.w;
                sb += B2.z - B0.y;
            }
            UPD(2); EMIT(2);
            if (vs) {
                const float4 Ab = wA[hb + 11][(wo + hb + 11) & 15];
                sx += Ab.x - A2.x; sy += Ab.y - A2.y;
                sz += Ab.z - A2.z; sw += Ab.w - A2.w;
                sb += B2.w - B0.z;
            }
            UPD(3); EMIT(3);
#undef UPD
#undef EMIT

            __syncthreads();   // drains glds prefetch; wA/wB safe to overwrite
        }
    }

    // ---- block reduction (2 waves) ----
#pragma unroll
    for (int off = 32; off > 0; off >>= 1) acc += __shfl_down(acc, off, 64);
    if (lane == 0) red[wid] = acc;
    __syncthreads();
    if (tid == 0) {
        atomicAdd(out, (red[0] + red[1]) * (float)(-1.0 / NTOT));
    }
}

extern "C" void kernel_launch(void* const* d_in, const int* in_sizes, int n_in,
                              void* d_out, int out_size, void* d_ws, size_t ws_size,
                              hipStream_t stream) {
    const float* I = (const float*)d_in[0];
    const float* T = (const float*)d_in[1];
    float* out = (float*)d_out;
    float* ws  = (float*)d_ws;

    init_kernel<<<dim3(1), dim3(1), 0, stream>>>(out, ws);

    dim3 grid(DIM_W / TW, DIM_H / TH, DIM_B * NCH);  // 10 x 6 x 12 = 720
    dim3 block(128);
    lncc3d_kernel<<<grid, block, 0, stream>>>(I, T, ws, out);
}

// Round 6
// 183.555 us; speedup vs baseline: 1.1312x; 1.1312x over previous
//
#include <hip/hip_runtime.h>

#define DIM_W 160
#define DIM_H 192
#define DIM_D 160
#define DIM_B 2

constexpr int TW = 16;      // output tile width
constexpr int TH = 32;      // output tile height (P=2 px/thread in H)
constexpr int CH = 19;      // depth outputs per chunk (27 slices = 3 x 9)
constexpr int NCH = 9;      // ceil(160/19)
constexpr int RH = TH + 8;  // 40 region rows
constexpr int RS = 36;      // region row stride (144B, 16B-aligned)
constexpr float INV_K = 1.0f / 729.0f;
constexpr double NTOT = 9830400.0;

__global__ void zero_out_kernel(float* out) { out[0] = 0.0f; }

__global__ __launch_bounds__(256)
void lncc3d_kernel(const float* __restrict__ I,
                   const float* __restrict__ T,
                   float* __restrict__ out)
{
    __shared__ __align__(16) float sR[2][2][RH][RS];  // [buf][field][row][col]
    __shared__ float4 wA[RH][17];   // (I,T,II,TT) W-sums
    __shared__ float  wB[RH][24];   // IT W-sums (2-way-free reads)
    __shared__ float red[4];

    const int tid = threadIdx.x;
    const int bw = blockIdx.x, bh = blockIdx.y, bz = blockIdx.z;
    const int b  = bz / NCH;
    const int c  = bz - b * NCH;
    const int w0 = bw * TW, h0 = bh * TH, d0 = c * CH;
    const int dEnd = min(d0 + CH, DIM_D);

    const int plane = DIM_H * DIM_W;
    const float* Ib = I + (size_t)b * DIM_D * plane;
    const float* Tb = T + (size_t)b * DIM_D * plane;

    const int wo = tid & 15;
    const int hb = (tid >> 4) << 1;

    // region-load mapping: item0 = tid (rows 0..31), item1 = tid+256 (wave 0 only)
    const int r0  = tid >> 3;
    const int c40 = (tid & 7) << 2;
    const int gh0 = h0 - 4 + r0;
    const int gw0 = w0 - 8 + c40;
    const bool inb0 = (gh0 >= 0 && gh0 < DIM_H && gw0 >= 0 && gw0 <= DIM_W - 4);
    const int soff0 = inb0 ? (gh0 * DIM_W + gw0) : 0;

    const int it1 = tid + 256;
    const int r1  = it1 >> 3;
    const int c41 = (it1 & 7) << 2;
    const int gh1 = h0 - 4 + r1;
    const int gw1 = w0 - 8 + c41;
    const bool w0q  = (tid < 64);                       // wave-uniform
    const bool inb1 = w0q && (gh1 >= 0 && gh1 < DIM_H && gw1 >= 0 && gw1 <= DIM_W - 4);
    const int soff1 = inb1 ? (gh1 * DIM_W + gw1) : 0;

    const float4 z4 = make_float4(0.f, 0.f, 0.f, 0.f);

    // D-rings (slot = static J) + running sums, 5 fields x 2 px
    float rgI[2][9], rgT[2][9], rgII[2][9], rgTT[2][9], rgIT[2][9];
    float rnI[2], rnT[2], rnII[2], rnTT[2], rnIT[2];
#pragma unroll
    for (int p = 0; p < 2; ++p) {
        rnI[p] = rnT[p] = rnII[p] = rnTT[p] = rnIT[p] = 0.0f;
#pragma unroll
        for (int q = 0; q < 9; ++q) {
            rgI[p][q] = rgT[p][q] = rgII[p][q] = rgTT[p][q] = rgIT[p][q] = 0.0f;
        }
    }
    float acc = 0.0f;

    const int sStart = d0 - 4;

    // two prefetch register sets, keyed to GLOBAL slice-index parity:
    // set a holds odd-parity slices, set b holds even-parity slices.
    float4 aI0 = z4, aT0 = z4, aI1 = z4, aT1 = z4;
    float4 bI0 = z4, bT0 = z4, bI1 = z4, bT1 = z4;

    // ---- prologue: slice sStart (parity 0) -> sR[0]; slice sStart+1 (parity 1) -> set a ----
    {
        int sc = min(max(sStart, 0), DIM_D - 1);
        const float* Is = Ib + (size_t)sc * plane;
        const float* Ts = Tb + (size_t)sc * plane;
        const float4 i0 = *(const float4*)(Is + soff0);
        const float4 t0 = *(const float4*)(Ts + soff0);
        *(float4*)&sR[0][0][r0][c40] = inb0 ? i0 : z4;
        *(float4*)&sR[0][1][r0][c40] = inb0 ? t0 : z4;
        if (w0q) {
            const float4 i1 = *(const float4*)(Is + soff1);
            const float4 t1 = *(const float4*)(Ts + soff1);
            *(float4*)&sR[0][0][r1][c41] = inb1 ? i1 : z4;
            *(float4*)&sR[0][1][r1][c41] = inb1 ? t1 : z4;
        }
        sc = min(max(sStart + 1, 0), DIM_D - 1);
        Is = Ib + (size_t)sc * plane;
        Ts = Tb + (size_t)sc * plane;
        aI0 = *(const float4*)(Is + soff0);
        aT0 = *(const float4*)(Ts + soff0);
        if (w0q) {
            aI1 = *(const float4*)(Is + soff1);
            aT1 = *(const float4*)(Ts + soff1);
        }
    }
    __syncthreads();

// PAR = parity of global slice index idx = T9+J (compile-time literal).
// incoming (slice idx+2, parity PAR): a if PAR==1 else b
// pending  (slice idx+1, parity PAR^1): a if PAR==0 else b
#define IN_I0(PAR) ((PAR) ? aI0 : bI0)
#define IN_T0(PAR) ((PAR) ? aT0 : bT0)
#define IN_I1(PAR) ((PAR) ? aI1 : bI1)
#define IN_T1(PAR) ((PAR) ? aT1 : bT1)
#define PD_I0(PAR) ((PAR) ? bI0 : aI0)
#define PD_T0(PAR) ((PAR) ? bT0 : aT0)
#define PD_I1(PAR) ((PAR) ? bI1 : aI1)
#define PD_T1(PAR) ((PAR) ? bT1 : aT1)

#define ITER(T9, J, PAR) { \
    const int s = sStart + (T9) + (J); \
    const bool vs = (s >= 0) && (s < DIM_D); \
    { /* 1. issue loads for slice s+2 (unconditional, clamped) */ \
        const int sc = min(max(s + 2, 0), DIM_D - 1); \
        const float* Is = Ib + (size_t)sc * plane; \
        const float* Ts = Tb + (size_t)sc * plane; \
        IN_I0(PAR) = *(const float4*)(Is + soff0); \
        IN_T0(PAR) = *(const float4*)(Ts + soff0); \
        if (w0q) { \
            IN_I1(PAR) = *(const float4*)(Is + soff1); \
            IN_T1(PAR) = *(const float4*)(Ts + soff1); \
        } \
    } \
    if (vs && tid < 160) { /* 2. stage 1 on sR[PAR] */ \
        const int r = tid >> 2; \
        const int g = tid & 3; \
        const float* rIp = &sR[(PAR)][0][r][0]; \
        const float* rTp = &sR[(PAR)][1][r][0]; \
        const float4 ia  = *(const float4*)(rIp + ((g + 1) << 2)); \
        const float4 ib4 = *(const float4*)(rIp + ((g + 2) << 2)); \
        const float4 ic4 = *(const float4*)(rIp + ((g + 3) << 2)); \
        const float4 ta  = *(const float4*)(rTp + ((g + 1) << 2)); \
        const float4 tb4 = *(const float4*)(rTp + ((g + 2) << 2)); \
        const float4 tc4 = *(const float4*)(rTp + ((g + 3) << 2)); \
        const float iv[12] = {ia.x, ia.y, ia.z, ia.w, ib4.x, ib4.y, ib4.z, ib4.w, \
                              ic4.x, ic4.y, ic4.z, ic4.w}; \
        const float tv[12] = {ta.x, ta.y, ta.z, ta.w, tb4.x, tb4.y, tb4.z, tb4.w, \
                              tc4.x, tc4.y, tc4.z, tc4.w}; \
        float aI = 0.f, aT = 0.f, aII = 0.f, aTT = 0.f, aIT = 0.f; \
        _Pragma("unroll") \
        for (int k = 0; k < 9; ++k) { \
            aI += iv[k]; aT += tv[k]; \
            aII = fmaf(iv[k], iv[k], aII); \
            aTT = fmaf(tv[k], tv[k], aTT); \
            aIT = fmaf(iv[k], tv[k], aIT); \
        } \
        const int c0 = g << 2; \
        wA[r][c0] = make_float4(aI, aT, aII, aTT); \
        wB[r][c0] = aIT; \
        _Pragma("unroll") \
        for (int q = 1; q < 4; ++q) { \
            const float ni = iv[8 + q], oi = iv[q - 1]; \
            const float nt = tv[8 + q], ot = tv[q - 1]; \
            aI += ni - oi; aT += nt - ot; \
            aII = fmaf(ni, ni, fmaf(oi, -oi, aII)); \
            aTT = fmaf(nt, nt, fmaf(ot, -ot, aTT)); \
            aIT = fmaf(ni, nt, fmaf(oi, -ot, aIT)); \
            wA[r][c0 + q] = make_float4(aI, aT, aII, aTT); \
            wB[r][c0 + q] = aIT; \
        } \
    } \
    __syncthreads(); \
    { /* 3. stage 2 + rings(slot J) + emit */ \
        float s2I0, s2T0, s2II0, s2TT0, s2IT0, s2I1, s2T1, s2II1, s2TT1, s2IT1; \
        if (vs) { \
            const float4 A0 = wA[hb][wo]; \
            const float  e0 = wB[hb][wo]; \
            float sx = A0.x, sy = A0.y, szv = A0.z, swv = A0.w, sbv = e0; \
            _Pragma("unroll") \
            for (int k = 1; k < 9; ++k) { \
                const float4 Ak = wA[hb + k][wo]; \
                sx += Ak.x; sy += Ak.y; szv += Ak.z; swv += Ak.w; \
                sbv += wB[hb + k][wo]; \
            } \
            const float4 A9 = wA[hb + 9][wo]; \
            const float  e9 = wB[hb + 9][wo]; \
            s2I0 = sx; s2T0 = sy; s2II0 = szv; s2TT0 = swv; s2IT0 = sbv; \
            s2I1  = sx  - A0.x + A9.x; \
            s2T1  = sy  - A0.y + A9.y; \
            s2II1 = szv - A0.z + A9.z; \
            s2TT1 = swv - A0.w + A9.w; \
            s2IT1 = sbv - e0   + e9; \
        } else { \
            s2I0 = s2T0 = s2II0 = s2TT0 = s2IT0 = 0.f; \
            s2I1 = s2T1 = s2II1 = s2TT1 = s2IT1 = 0.f; \
        } \
        rnI[0]  += s2I0  - rgI[0][(J)];  rgI[0][(J)]  = s2I0; \
        rnT[0]  += s2T0  - rgT[0][(J)];  rgT[0][(J)]  = s2T0; \
        rnII[0] += s2II0 - rgII[0][(J)]; rgII[0][(J)] = s2II0; \
        rnTT[0] += s2TT0 - rgTT[0][(J)]; rgTT[0][(J)] = s2TT0; \
        rnIT[0] += s2IT0 - rgIT[0][(J)]; rgIT[0][(J)] = s2IT0; \
        rnI[1]  += s2I1  - rgI[1][(J)];  rgI[1][(J)]  = s2I1; \
        rnT[1]  += s2T1  - rgT[1][(J)];  rgT[1][(J)]  = s2T1; \
        rnII[1] += s2II1 - rgII[1][(J)]; rgII[1][(J)] = s2II1; \
        rnTT[1] += s2TT1 - rgTT[1][(J)]; rgTT[1][(J)] = s2TT1; \
        rnIT[1] += s2IT1 - rgIT[1][(J)]; rgIT[1][(J)] = s2IT1; \
        if ((s >= d0 + 4) && ((s - 4) < dEnd)) { \
            float cr, vv, tvv; \
            cr  = rnIT[0] - rnI[0] * rnT[0] * INV_K; \
            vv  = rnII[0] - rnI[0] * rnI[0] * INV_K; \
            tvv = rnTT[0] - rnT[0] * rnT[0] * INV_K; \
            acc += cr * cr * __builtin_amdgcn_rcpf(fmaf(tvv, vv, 1e-5f)); \
            cr  = rnIT[1] - rnI[1] * rnT[1] * INV_K; \
            vv  = rnII[1] - rnI[1] * rnI[1] * INV_K; \
            tvv = rnTT[1] - rnT[1] * rnT[1] * INV_K; \
            acc += cr * cr * __builtin_amdgcn_rcpf(fmaf(tvv, vv, 1e-5f)); \
        } \
    } \
    { /* 4. commit pending (slice s+1, parity PAR^1) into sR[PAR^1] */ \
        *(float4*)&sR[(PAR) ^ 1][0][r0][c40] = inb0 ? PD_I0(PAR) : z4; \
        *(float4*)&sR[(PAR) ^ 1][1][r0][c40] = inb0 ? PD_T0(PAR) : z4; \
        if (w0q) { \
            *(float4*)&sR[(PAR) ^ 1][0][r1][c41] = inb1 ? PD_I1(PAR) : z4; \
            *(float4*)&sR[(PAR) ^ 1][1][r1][c41] = inb1 ? PD_T1(PAR) : z4; \
        } \
    } \
    __syncthreads(); \
}

// one pass of 9 slices; P0 = parity of (T9+even J), P1 = parity of (T9+odd J)
#define PASS(T9, P0, P1) \
    ITER(T9, 0, P0) ITER(T9, 1, P1) ITER(T9, 2, P0) ITER(T9, 3, P1) \
    ITER(T9, 4, P0) ITER(T9, 5, P1) ITER(T9, 6, P0) ITER(T9, 7, P1) \
    ITER(T9, 8, P0)

    PASS(0, 0, 1)
    PASS(9, 1, 0)
    PASS(18, 0, 1)

#undef PASS
#undef ITER
#undef IN_I0
#undef IN_T0
#undef IN_I1
#undef IN_T1
#undef PD_I0
#undef PD_T0
#undef PD_I1
#undef PD_T1

    // ---- block reduction ----
#pragma unroll
    for (int off = 32; off > 0; off >>= 1) acc += __shfl_down(acc, off, 64);
    if ((tid & 63) == 0) red[tid >> 6] = acc;
    __syncthreads();
    if (tid == 0) {
        const float bs = red[0] + red[1] + red[2] + red[3];
        atomicAdd(out, bs * (float)(-1.0 / NTOT));
    }
}

extern "C" void kernel_launch(void* const* d_in, const int* in_sizes, int n_in,
                              void* d_out, int out_size, void* d_ws, size_t ws_size,
                              hipStream_t stream) {
    const float* I = (const float*)d_in[0];
    const float* T = (const float*)d_in[1];
    float* out = (float*)d_out;

    zero_out_kernel<<<dim3(1), dim3(1), 0, stream>>>(out);

    dim3 grid(DIM_W / TW, DIM_H / TH, DIM_B * NCH); // 10 x 6 x 18 = 1080
    dim3 block(256);
    lncc3d_kernel<<<grid, block, 0, stream>>>(I, T, out);
}

// Round 7
// 83.041 us; speedup vs baseline: 2.5005x; 2.2104x over previous
//
#include <hip/hip_runtime.h>

#define DIM_W 160
#define DIM_H 192
#define DIM_D 160
#define DIM_B 2

constexpr int TW = 16;      // output tile width
constexpr int TH = 32;      // output tile height (P=2 px/thread in H)
constexpr int CH = 19;      // depth outputs per chunk (27 slices = 3 x 9)
constexpr int NCH = 9;      // ceil(160/19)
constexpr int RH = TH + 8;  // 40 region rows
constexpr float INV_K = 1.0f / 729.0f;
constexpr double NTOT = 9830400.0;

typedef unsigned int u32;
typedef __attribute__((address_space(1))) const u32 gu32;
typedef __attribute__((address_space(3))) u32 lu32;

__global__ void init_kernel(float* out, float* ws) {
    out[0] = 0.0f;
    ws[0] = 0.0f; ws[1] = 0.0f; ws[2] = 0.0f; ws[3] = 0.0f;
}

__device__ __forceinline__ int clampD(int s) {
    return s < 0 ? 0 : (s > DIM_D - 1 ? DIM_D - 1 : s);
}

__global__ __launch_bounds__(256)
void lncc3d_kernel(const float* __restrict__ I,
                   const float* __restrict__ T,
                   const float* __restrict__ zsrc,
                   float* __restrict__ out)
{
    // slice region, glds-staged: [buf][field][row][32 words]. Row = 128B,
    // logical f4 q of row r stored at physical f4 (q+r)&7 (source-side rotation).
    __shared__ __align__(16) float sR[2][2][RH][32];
    // W-sums (I,T,II,TT): float4, column rotated (c+row)&15
    __shared__ __align__(16) float4 wA[RH][16];
    // W-sums IT, transposed [w][row], stride 44
    __shared__ __align__(16) float  wB[16][44];
    __shared__ float red[4];

    const int tid  = threadIdx.x;
    const int lane = tid & 63;
    const int wid  = tid >> 6;
    const int wo   = tid & 15;
    const int hb   = (tid >> 4) << 1;

    const int bw = blockIdx.x, bh = blockIdx.y, bz = blockIdx.z;
    const int b  = bz / NCH;
    const int c  = bz - b * NCH;
    const int w0 = bw * TW, h0 = bh * TH, d0 = c * CH;
    const int dEnd = min(d0 + CH, DIM_D);

    const int plane = DIM_H * DIM_W;
    const int fld  = wid >> 1;            // 0: field I, 1: field T
    const int kodd = wid & 1;             // chunk set {1,3} vs {0,2,4}
    const int nck  = kodd ? 2 : 3;        // glds per wave per slice
    const float* Fb = (fld ? T : I) + (size_t)b * DIM_D * plane;

    // per-lane glds source offsets (rotation folded into source address)
    int boff[3], crw[3];
#pragma unroll
    for (int i = 0; i < 3; ++i) {
        const int ck  = kodd ? (2 * i + 1) : (2 * i);
        const int row = 8 * ck + (lane >> 3);
        const int pf4 = lane & 7;
        const int lf4 = (pf4 - row) & 7;
        const int gh  = h0 - 4 + row;
        const int gw  = w0 - 8 + (lf4 << 2);
        crw[i]  = 8 * ck;
        boff[i] = (i < nck && gh >= 0 && gh < DIM_H && gw >= 0 && gw <= DIM_W - 4)
                  ? (gh * DIM_W + gw) : -1;
    }

    auto issue = [&](int sc, int buf) {
        const float* Fs = Fb + (size_t)sc * plane;
#pragma unroll
        for (int i = 0; i < 3; ++i) {
            if (i < nck) {
                const float* gp = (boff[i] >= 0) ? (Fs + boff[i]) : zsrc;
                __builtin_amdgcn_global_load_lds((gu32*)gp, (lu32*)&sR[buf][fld][crw[i]][0],
                                                 16, 0, 0);
            }
        }
    };

    // D-rings (slot = static J) + running sums, 5 fields x 2 px
    float rgI[2][9], rgT[2][9], rgII[2][9], rgTT[2][9], rgIT[2][9];
    float rnI[2], rnT[2], rnII[2], rnTT[2], rnIT[2];
#pragma unroll
    for (int p = 0; p < 2; ++p) {
        rnI[p] = rnT[p] = rnII[p] = rnTT[p] = rnIT[p] = 0.0f;
#pragma unroll
        for (int q = 0; q < 9; ++q) {
            rgI[p][q] = rgT[p][q] = rgII[p][q] = rgTT[p][q] = rgIT[p][q] = 0.0f;
        }
    }
    float acc = 0.0f;

    const int sStart = d0 - 4;
    int cur = 0;

    // ---- prologue: stage sStart -> buf0, sStart+1 -> buf1 ----
    issue(clampD(sStart), 0);
    issue(clampD(sStart + 1), 1);
    // certify own glds for sStart done (leave sStart+1's in flight), then publish
    if (kodd) { asm volatile("s_waitcnt vmcnt(2)" ::: "memory"); }
    else      { asm volatile("s_waitcnt vmcnt(3)" ::: "memory"); }
    __builtin_amdgcn_s_barrier();

    for (int t = 0; t < 3; ++t) {
        const int t9 = t * 9;
#pragma unroll
        for (int j = 0; j < 9; ++j) {
            const int s  = sStart + t9 + j;
            const bool vs = (s >= 0) && (s < DIM_D);

            // ---- stage 1: 9-wide W sums on sR[cur] ----
            if (vs && tid < 160) {
                const int r = tid >> 2;
                const int g = tid & 3;
                const float* rIp = &sR[cur][0][r][0];
                const float* rTp = &sR[cur][1][r][0];
                const int q0 = ((g + 1 + r) & 7) << 2;
                const int q1 = ((g + 2 + r) & 7) << 2;
                const int q2 = ((g + 3 + r) & 7) << 2;
                const float4 ia  = *(const float4*)(rIp + q0);
                const float4 ib4 = *(const float4*)(rIp + q1);
                const float4 ic4 = *(const float4*)(rIp + q2);
                const float4 ta  = *(const float4*)(rTp + q0);
                const float4 tb4 = *(const float4*)(rTp + q1);
                const float4 tc4 = *(const float4*)(rTp + q2);
                const float iv[12] = {ia.x, ia.y, ia.z, ia.w, ib4.x, ib4.y, ib4.z, ib4.w,
                                      ic4.x, ic4.y, ic4.z, ic4.w};
                const float tv[12] = {ta.x, ta.y, ta.z, ta.w, tb4.x, tb4.y, tb4.z, tb4.w,
                                      tc4.x, tc4.y, tc4.z, tc4.w};
                float aI = 0.f, aT = 0.f, aII = 0.f, aTT = 0.f, aIT = 0.f;
#pragma unroll
                for (int k = 0; k < 9; ++k) {
                    aI += iv[k]; aT += tv[k];
                    aII = fmaf(iv[k], iv[k], aII);
                    aTT = fmaf(tv[k], tv[k], aTT);
                    aIT = fmaf(iv[k], tv[k], aIT);
                }
                const int c0 = g << 2;
                wA[r][(c0 + r) & 15] = make_float4(aI, aT, aII, aTT);
                wB[c0][r] = aIT;
#pragma unroll
                for (int q = 1; q < 4; ++q) {
                    const float ni = iv[8 + q], oi = iv[q - 1];
                    const float nt = tv[8 + q], ot = tv[q - 1];
                    aI += ni - oi; aT += nt - ot;
                    aII = fmaf(ni, ni, fmaf(oi, -oi, aII));
                    aTT = fmaf(nt, nt, fmaf(ot, -ot, aTT));
                    aIT = fmaf(ni, nt, fmaf(oi, -ot, aIT));
                    wA[r][(c0 + q + r) & 15] = make_float4(aI, aT, aII, aTT);
                    wB[c0 + q][r] = aIT;
                }
            }
            asm volatile("s_waitcnt lgkmcnt(0)" ::: "memory");
            __builtin_amdgcn_s_barrier();   // D: wA/wB published; sR[cur] reads done

            // ---- issue glds for slice s+2 into sR[cur] (safe: readers done) ----
            issue(clampD(s + 2), cur);

            // ---- stage 2: 9-tall H sums (2 px), rings slot j, emit ----
            float s2I0, s2T0, s2II0, s2TT0, s2IT0, s2I1, s2T1, s2II1, s2TT1, s2IT1;
            if (vs) {
                const float4 A0 = wA[hb][(wo + hb) & 15];
                float sx = A0.x, sy = A0.y, szv = A0.z, swv = A0.w;
#pragma unroll
                for (int k = 1; k < 9; ++k) {
                    const float4 Ak = wA[hb + k][(wo + hb + k) & 15];
                    sx += Ak.x; sy += Ak.y; szv += Ak.z; swv += Ak.w;
                }
                const float4 A9 = wA[hb + 9][(wo + hb + 9) & 15];
                const float2 B0 = *(const float2*)&wB[wo][hb];
                const float2 B1 = *(const float2*)&wB[wo][hb + 2];
                const float2 B2 = *(const float2*)&wB[wo][hb + 4];
                const float2 B3 = *(const float2*)&wB[wo][hb + 6];
                const float2 B4 = *(const float2*)&wB[wo][hb + 8];
                const float sbv = B0.x + B0.y + B1.x + B1.y + B2.x + B2.y
                                + B3.x + B3.y + B4.x;
                s2I0 = sx; s2T0 = sy; s2II0 = szv; s2TT0 = swv; s2IT0 = sbv;
                s2I1  = sx  - A0.x + A9.x;
                s2T1  = sy  - A0.y + A9.y;
                s2II1 = szv - A0.z + A9.z;
                s2TT1 = swv - A0.w + A9.w;
                s2IT1 = sbv - B0.x + B4.y;
            } else {
                s2I0 = s2T0 = s2II0 = s2TT0 = s2IT0 = 0.f;
                s2I1 = s2T1 = s2II1 = s2TT1 = s2IT1 = 0.f;
            }

            rnI[0]  += s2I0  - rgI[0][j];  rgI[0][j]  = s2I0;
            rnT[0]  += s2T0  - rgT[0][j];  rgT[0][j]  = s2T0;
            rnII[0] += s2II0 - rgII[0][j]; rgII[0][j] = s2II0;
            rnTT[0] += s2TT0 - rgTT[0][j]; rgTT[0][j] = s2TT0;
            rnIT[0] += s2IT0 - rgIT[0][j]; rgIT[0][j] = s2IT0;
            rnI[1]  += s2I1  - rgI[1][j];  rgI[1][j]  = s2I1;
            rnT[1]  += s2T1  - rgT[1][j];  rgT[1][j]  = s2T1;
            rnII[1] += s2II1 - rgII[1][j]; rgII[1][j] = s2II1;
            rnTT[1] += s2TT1 - rgTT[1][j]; rgTT[1][j] = s2TT1;
            rnIT[1] += s2IT1 - rgIT[1][j]; rgIT[1][j] = s2IT1;

            if ((s >= d0 + 4) && ((s - 4) < dEnd)) {
                float cr, vv, tvv;
                cr  = rnIT[0] - rnI[0] * rnT[0] * INV_K;
                vv  = rnII[0] - rnI[0] * rnI[0] * INV_K;
                tvv = rnTT[0] - rnT[0] * rnT[0] * INV_K;
                acc += cr * cr * __builtin_amdgcn_rcpf(fmaf(tvv, vv, 1e-5f));
                cr  = rnIT[1] - rnI[1] * rnT[1] * INV_K;
                vv  = rnII[1] - rnI[1] * rnI[1] * INV_K;
                tvv = rnTT[1] - rnT[1] * rnT[1] * INV_K;
                acc += cr * cr * __builtin_amdgcn_rcpf(fmaf(tvv, vv, 1e-5f));
            }

            // ---- F: wA/wB reads done; certify own glds for slice s+1 landed
            // (leave s+2's k in flight), then publish to all waves ----
            asm volatile("s_waitcnt lgkmcnt(0)" ::: "memory");
            if (kodd) { asm volatile("s_waitcnt vmcnt(2)" ::: "memory"); }
            else      { asm volatile("s_waitcnt vmcnt(3)" ::: "memory"); }
            __builtin_amdgcn_s_barrier();
            cur ^= 1;
        }
    }

    // ---- block reduction ----
#pragma unroll
    for (int off = 32; off > 0; off >>= 1) acc += __shfl_down(acc, off, 64);
    if (lane == 0) red[wid] = acc;
    __syncthreads();
    if (tid == 0) {
        const float bs = red[0] + red[1] + red[2] + red[3];
        atomicAdd(out, bs * (float)(-1.0 / NTOT));
    }
}

extern "C" void kernel_launch(void* const* d_in, const int* in_sizes, int n_in,
                              void* d_out, int out_size, void* d_ws, size_t ws_size,
                              hipStream_t stream) {
    const float* I = (const float*)d_in[0];
    const float* T = (const float*)d_in[1];
    float* out = (float*)d_out;
    float* ws  = (float*)d_ws;

    init_kernel<<<dim3(1), dim3(1), 0, stream>>>(out, ws);

    dim3 grid(DIM_W / TW, DIM_H / TH, DIM_B * NCH); // 10 x 6 x 18 = 1080
    dim3 block(256);
    lncc3d_kernel<<<grid, block, 0, stream>>>(I, T, ws, out);
}